// Round 2
// 287.743 us; speedup vs baseline: 1.2308x; 1.2308x over previous
//
#include <hip/hip_runtime.h>

// SABlock: x(4,512,64,64) -> phi/theta/g (1x1 convs, CI=256) -> f=theta^T@phi
// -> softmax -> y=a@g^T -> w_mask 1x1 conv -> out(4,512,64,64)
// All GEMMs fp16-in / fp32-accumulate on MFMA 16x16x32_f16.
// Round 5: in-block kv-split. 256 blocks x 512 threads: wave-group 0-3 runs
// kv [0,2048), group 4-7 runs [2048,4096) for the SAME 64 q-rows — each group
// is the verified v3 pipeline (own 3-buffer ring, own vmcnt(4) stream).
// f32 merge through LDS at the end (no global partials, no merge kernel).
// 8 waves/CU = 2 waves/SIMD (was 1): doubles latency hiding.

#define BB 4
#define CC 512
#define NN_SP 4096   // H*W
#define CI 256

typedef _Float16 f16x8 __attribute__((ext_vector_type(8)));
typedef float f32x4 __attribute__((ext_vector_type(4)));

__device__ __forceinline__ void async16(const void* gsrc, void* ldst) {
  __builtin_amdgcn_global_load_lds(
      (const __attribute__((address_space(1))) unsigned int*)gsrc,
      (__attribute__((address_space(3))) unsigned int*)ldst, 16, 0, 0);
}

// ---------------- weight convert: fp32 -> f16, stack [w_phi; w_theta] ----------------
__global__ __launch_bounds__(256) void convert_w(
    const float* __restrict__ wphi, const float* __restrict__ wtheta,
    const float* __restrict__ wg, const float* __restrict__ wmask,
    _Float16* __restrict__ wpt, _Float16* __restrict__ wgh, _Float16* __restrict__ wmh) {
  int i = blockIdx.x * 256 + threadIdx.x;
  if (i < 512 * 512) {                       // wpt rows: 0..255 phi, 256..511 theta
    int row = i >> 9, k = i & 511;
    float v = (row < 256) ? wphi[row * 512 + k] : wtheta[(row - 256) * 512 + k];
    wpt[i] = (_Float16)v;
  } else if (i < 512 * 512 + 256 * 512) {
    int j = i - 512 * 512;
    wgh[j] = (_Float16)wg[j];
  } else {
    int j = i - 512 * 512 - 256 * 512;
    wmh[j] = (_Float16)wmask[j];
  }
}

// ---------------- x (B,512,4096) fp32 -> x_T (B,4096,512) f16 ----------------
__global__ __launch_bounds__(256) void transpose_x(const float* __restrict__ x,
                                                   _Float16* __restrict__ xT) {
  __shared__ float tile[64][65];   // +1 pad: conflict-free column read
  const int n0 = blockIdx.x * 64, c0 = blockIdx.y * 64, b = blockIdx.z;
  const int tx = threadIdx.x & 63, ty = threadIdx.x >> 6;
  const float* xb = x + (long long)b * CC * NN_SP;
#pragma unroll
  for (int i = 0; i < 16; ++i) {
    int row = i * 4 + ty;
    tile[row][tx] = xb[(long long)(c0 + row) * NN_SP + n0 + tx];
  }
  __syncthreads();
  _Float16* xTb = xT + (long long)b * NN_SP * CC;
#pragma unroll
  for (int i = 0; i < 16; ++i) {
    int row = i * 4 + ty;
    xTb[(long long)(n0 + row) * CC + c0 + tx] = (_Float16)tile[tx][row];
  }
}

// ---------------- generic gemm_bt: C[m,n] = sum_k A[m,k] * Bt[n,k] ----------------
// m97 structure: global_load_lds width-16 staging, 4 waves 2x2, 16 MFMA/wave/K-step.
template <int M, int NT, int K, bool F16OUT>
__global__ __launch_bounds__(256, 2) void gemm_bt(
    const _Float16* __restrict__ Ab, const _Float16* __restrict__ Btb,
    void* __restrict__ Cb, long long sA, long long sB, long long sC) {
  __shared__ _Float16 As[128 * 32];
  __shared__ _Float16 Bs[128 * 32];
  const int tid = threadIdx.x, lane = tid & 63, w = tid >> 6;
  const int wm = w >> 1, wn = w & 1;
  const int l15 = lane & 15, lq = lane >> 4;
  const int b = blockIdx.z;
  const _Float16* A = Ab + (long long)b * sA;
  const _Float16* Bt = Btb + (long long)b * sB;
  const int m0 = blockIdx.y * 128, n0 = blockIdx.x * 128;

  f32x4 acc[4][4];
#pragma unroll
  for (int i = 0; i < 4; ++i)
#pragma unroll
    for (int j = 0; j < 4; ++j) acc[i][j] = (f32x4){0.f, 0.f, 0.f, 0.f};

  for (int k0 = 0; k0 < K; k0 += 32) {
    __syncthreads();  // previous LDS reads done before overwrite
#pragma unroll
    for (int j = 0; j < 2; ++j) {
      int chw = j * 256 + w * 64;      // wave-uniform chunk base
      int ch = chw + lane;
      int row = ch >> 2, kc = ch & 3;  // 4 x 16B chunks per 32-k row segment
      async16(A + (long long)(m0 + row) * K + k0 + kc * 8, (void*)(As + chw * 8));
      async16(Bt + (long long)(n0 + row) * K + k0 + kc * 8, (void*)(Bs + chw * 8));
    }
    __syncthreads();  // vmcnt(0) drain + barrier
    f16x8 af[4], bf[4];
#pragma unroll
    for (int mt = 0; mt < 4; ++mt)
      af[mt] = *(const f16x8*)(As + (wm * 64 + mt * 16 + l15) * 32 + lq * 8);
#pragma unroll
    for (int nt = 0; nt < 4; ++nt)
      bf[nt] = *(const f16x8*)(Bs + (wn * 64 + nt * 16 + l15) * 32 + lq * 8);
#pragma unroll
    for (int mt = 0; mt < 4; ++mt)
#pragma unroll
      for (int nt = 0; nt < 4; ++nt)
        acc[mt][nt] = __builtin_amdgcn_mfma_f32_16x16x32_f16(af[mt], bf[nt], acc[mt][nt], 0, 0, 0);
  }

#pragma unroll
  for (int mt = 0; mt < 4; ++mt)
#pragma unroll
    for (int nt = 0; nt < 4; ++nt)
#pragma unroll
      for (int r = 0; r < 4; ++r) {
        int row = m0 + wm * 64 + mt * 16 + lq * 4 + r;  // C/D: row=(lane>>4)*4+reg
        int col = n0 + wn * 64 + nt * 16 + l15;         //      col=lane&15
        if (F16OUT)
          ((_Float16*)Cb + (long long)b * sC)[(long long)row * NT + col] = (_Float16)acc[mt][nt][r];
        else
          ((float*)Cb + (long long)b * sC)[(long long)row * NT + col] = acc[mt][nt][r];
      }
}

// ---------------- flash attention v5: in-block kv-split ----------------
// pt (B,4096,512): cols 0..255 = phi_T, 256..511 = theta_T (c-contiguous)
// g  (B,256,4096): kv-contiguous.  yT (B,4096,256) f16 out.
// 256 blocks x 512 threads. Wave-group hw=w>>2 handles kv half hw for the
// block's 64 q-rows; wave wp=w&3 in each group owns 16 q-rows (same rows as
// its partner wave wp+4). Per group: v3's exact pipeline — 16 kv-steps of
// 128, 8 staging phases each into Stg[hw] 3-buffer ring, vmcnt(4) counted
// waits (per-wave counters => identical semantics to v3). End: group 1 dumps
// unnormalized yacc + (m,l) f32 into LDS (staging area is dead), group 0
// merges in f32 and stores yT.
__global__ __launch_bounds__(512, 2) void flash_attn3(
    const _Float16* __restrict__ pt, const _Float16* __restrict__ g,
    _Float16* __restrict__ yT) {
  __shared__ _Float16 Stg[2][3][8192];  // per-group 3 x 16KB ring (96KB)
  __shared__ _Float16 Ps[8][2048];      // per-wave P [16q][128kv] A-frag order (32KB)
  const int tid = threadIdx.x, lane = tid & 63, w = tid >> 6;
  const int hw = w >> 2, wp = w & 3;    // kv-half group, wave-in-group
  const int l15 = lane & 15, lq = lane >> 4;

  // XCD swizzle: 2 XCDs per batch -> per-XCD L2 working set = one batch's ~4MB
  const int idx = blockIdx.x;
  const int b = (idx >> 1) & 3;
  const int q0 = (((idx >> 3) << 1) | (idx & 1)) * 64;
  const int kvbase = hw * 2048;
  const _Float16* __restrict__ ptb = pt + (long long)b * NN_SP * 512;
  const _Float16* __restrict__ gb = g + (long long)b * CI * NN_SP;

  // Per-issue lane offsets (frag-order permutation), invariant over phases.
  // phi chunk [128kv][64ch]: unit u -> (k2=u>>9, nv=(u>>6)&7, r15=(u>>2)&15, rq=u&3)
  //   src elem = (kv0 + nv*16 + r15)*512 + (c*64 + k2*32 + rq*8)
  // g chunk [64c][128kv]: unit u -> (kq=u>>8, ct=(u>>6)&3, r15, rq)
  //   src elem = (c0 + ct*16 + r15)*4096 + (kv0 + kq*32 + rq*8)
  int offPhi[4], offG[4], chw_[4];
#pragma unroll
  for (int j = 0; j < 4; ++j) {
    int u = wp * 256 + j * 64 + lane;
    chw_[j] = wp * 256 + j * 64;
    int k2 = u >> 9, nv8 = (u >> 6) & 7, r15 = (u >> 2) & 15, rq = u & 3;
    offPhi[j] = (nv8 * 16 + r15) * 512 + k2 * 32 + rq * 8;
    int kq = u >> 8, ct4 = (u >> 6) & 3;
    offG[j] = (ct4 * 16 + r15) * 4096 + kq * 32 + rq * 8;
  }

  // Q (theta) resident in registers: 16 q-rows (shared with partner wave)
  f16x8 qreg[8];
#pragma unroll
  for (int kk = 0; kk < 8; ++kk)
    qreg[kk] = *(const f16x8*)(
        ptb + (long long)(q0 + wp * 16 + l15) * 512 + 256 + kk * 32 + lq * 8);

  f32x4 yacc[16];
#pragma unroll
  for (int nt = 0; nt < 16; ++nt) yacc[nt] = (f32x4){0.f, 0.f, 0.f, 0.f};
  float mrow[4] = {-3e38f, -3e38f, -3e38f, -3e38f};
  float lrow[4] = {0.f, 0.f, 0.f, 0.f};

  // issue phase q into this group's buffer bi (4 async16 per wave = 4 vm ops)
  auto issue = [&](int q, int bi) {
    if (q >= 128) return;            // 16 kv-steps x 8 phases per group
    _Float16* buf = Stg[hw][bi];
    int tq = q >> 3, sub = q & 7, kv0 = kvbase + tq * 128;
    if (sub < 4) {
      const _Float16* basep = ptb + kv0 * 512 + sub * 64;
#pragma unroll
      for (int j = 0; j < 4; ++j)
        async16(basep + offPhi[j], (void*)(buf + chw_[j] * 8));
    } else {
      const _Float16* baseg = gb + (sub - 4) * 64 * 4096 + kv0;
#pragma unroll
      for (int j = 0; j < 4; ++j)
        async16(baseg + offG[j], (void*)(buf + chw_[j] * 8));
    }
  };

  int p = 0, bcur = 0;     // phase counter, ring position (p % 3)
  issue(0, 0);
  issue(1, 1);

  for (int t = 0; t < 16; ++t) {
    f32x4 S[8];
#pragma unroll
    for (int i = 0; i < 8; ++i) S[i] = (f32x4){0.f, 0.f, 0.f, 0.f};

    // ---- 4 phi phases: S = theta @ phi^T ----
#pragma unroll
    for (int c = 0; c < 4; ++c) {
      asm volatile("s_waitcnt vmcnt(4)" ::: "memory");  // phase p's loads done
      asm volatile("s_barrier" ::: "memory");           // all waves: data in, prev buf free
      int bn = bcur + 2; if (bn >= 3) bn -= 3;
      issue(p + 2, bn);
      const _Float16* buf = Stg[hw][bcur];
#pragma unroll
      for (int k2 = 0; k2 < 2; ++k2)
#pragma unroll
        for (int nv = 0; nv < 8; ++nv) {
          f16x8 bf = *(const f16x8*)(buf + (k2 * 512 + nv * 64 + l15 * 4 + lq) * 8);
          S[nv] = __builtin_amdgcn_mfma_f32_16x16x32_f16(qreg[c * 2 + k2], bf, S[nv], 0, 0, 0);
        }
      ++p; ++bcur; if (bcur == 3) bcur = 0;
    }

    // ---- wave-private online softmax (rows = lq*4+r, cols across l15) ----
    float alpha[4];
#pragma unroll
    for (int r = 0; r < 4; ++r) {
      float mx = fmaxf(fmaxf(S[0][r], S[1][r]), fmaxf(S[2][r], S[3][r]));
      mx = fmaxf(mx, fmaxf(fmaxf(S[4][r], S[5][r]), fmaxf(S[6][r], S[7][r])));
#pragma unroll
      for (int d = 1; d < 16; d <<= 1) mx = fmaxf(mx, __shfl_xor(mx, d, 64));
      float nm = fmaxf(mrow[r], mx);
      alpha[r] = __expf(mrow[r] - nm);
      mrow[r] = nm;
      float ps = 0.f;
#pragma unroll
      for (int nv = 0; nv < 8; ++nv) {
        float pv = __expf(S[nv][r] - nm);
        S[nv][r] = pv;
        ps += pv;
      }
#pragma unroll
      for (int d = 1; d < 16; d <<= 1) ps += __shfl_xor(ps, d, 64);
      lrow[r] = lrow[r] * alpha[r] + ps;
    }
    {
      f32x4 al = {alpha[0], alpha[1], alpha[2], alpha[3]};
#pragma unroll
      for (int nt = 0; nt < 16; ++nt) yacc[nt] *= al;
    }

    // ---- P: C/D regs -> wave-private LDS in A-frag order (r2 scheme) ----
#pragma unroll
    for (int nv = 0; nv < 8; ++nv) {
      int kq = nv >> 1;
      int lqr = (nv & 1) * 2 + (l15 >> 3);
      int e = l15 & 7;
#pragma unroll
      for (int r = 0; r < 4; ++r) {
        int u = kq * 64 + lqr * 16 + lq * 4 + r;
        Ps[w][u * 8 + e] = (_Float16)S[nv][r];
      }
    }
    f16x8 aP[4];
#pragma unroll
    for (int kq = 0; kq < 4; ++kq)
      aP[kq] = *(const f16x8*)(&Ps[w][(kq * 64 + lane) * 8]);

    // ---- 4 g phases: y += P @ g^T ----
#pragma unroll
    for (int cg = 0; cg < 4; ++cg) {
      if (t == 15 && cg == 3) {
        asm volatile("s_waitcnt vmcnt(0)" ::: "memory");  // final phase: nothing newer in flight
      } else {
        asm volatile("s_waitcnt vmcnt(4)" ::: "memory");
      }
      asm volatile("s_barrier" ::: "memory");
      int bn = bcur + 2; if (bn >= 3) bn -= 3;
      issue(p + 2, bn);
      const _Float16* buf = Stg[hw][bcur];
#pragma unroll
      for (int kq = 0; kq < 4; ++kq)
#pragma unroll
        for (int ct = 0; ct < 4; ++ct) {
          f16x8 bf = *(const f16x8*)(buf + (kq * 256 + ct * 64 + l15 * 4 + lq) * 8);
          yacc[cg * 4 + ct] =
              __builtin_amdgcn_mfma_f32_16x16x32_f16(aP[kq], bf, yacc[cg * 4 + ct], 0, 0, 0);
        }
      ++p; ++bcur; if (bcur == 3) bcur = 0;
    }
  }

  // ---- in-block f32 merge: group 1 -> LDS, group 0 combines + stores ----
  __syncthreads();  // all waves done with Stg before it is reused
  float* mbuf = (float*)Stg;                    // [64 rows][stride 257] f32 (~66KB)
  float* sbuf = (float*)((char*)Stg + 81920);   // [64 rows][2] f32 (m,l)
  if (hw == 1) {
#pragma unroll
    for (int r = 0; r < 4; ++r) {
      int rr = wp * 16 + lq * 4 + r;
#pragma unroll
      for (int nt = 0; nt < 16; ++nt)
        mbuf[rr * 257 + nt * 16 + l15] = yacc[nt][r];
      if (l15 == 0) {
        sbuf[rr * 2 + 0] = mrow[r];
        sbuf[rr * 2 + 1] = lrow[r];
      }
    }
  }
  __syncthreads();
  if (hw == 0) {
    _Float16* yTb = yT + (long long)b * NN_SP * CI;
#pragma unroll
    for (int r = 0; r < 4; ++r) {
      int rr = wp * 16 + lq * 4 + r;
      float m2 = sbuf[rr * 2 + 0], l2 = sbuf[rr * 2 + 1];
      float m = fmaxf(mrow[r], m2);
      float w1 = __expf(mrow[r] - m), w2 = __expf(m2 - m);
      float inv = 1.f / (w1 * lrow[r] + w2 * l2);
      int row = q0 + rr;
#pragma unroll
      for (int nt = 0; nt < 16; ++nt) {
        float v2 = mbuf[rr * 257 + nt * 16 + l15];
        yTb[(long long)row * CI + nt * 16 + l15] =
            (_Float16)((w1 * yacc[nt][r] + w2 * v2) * inv);
      }
    }
  }
}

extern "C" void kernel_launch(void* const* d_in, const int* in_sizes, int n_in,
                              void* d_out, int out_size, void* d_ws, size_t ws_size,
                              hipStream_t stream) {
  const float* x = (const float*)d_in[0];
  const float* w_phi = (const float*)d_in[1];
  const float* w_theta = (const float*)d_in[2];
  const float* w_g = (const float*)d_in[3];
  const float* w_mask = (const float*)d_in[4];
  float* out = (float*)d_out;
  char* ws = (char*)d_ws;

  // workspace layout (51.4 MB total)
  _Float16* xT = (_Float16*)(ws);                 // (B,4096,512)  16.78 MB
  _Float16* pt = (_Float16*)(ws + 16777216);      // (B,4096,512)  16.78 MB  [phi|theta]
  _Float16* gB = (_Float16*)(ws + 33554432);      // (B,256,4096)   8.39 MB
  _Float16* yT = (_Float16*)(ws + 41943040);      // (B,4096,256)   8.39 MB
  _Float16* wpt = (_Float16*)(ws + 50331648);     // (512,512)
  _Float16* wg = (_Float16*)(ws + 50855936);      // (256,512)
  _Float16* wm = (_Float16*)(ws + 51118080);      // (512,256)

  convert_w<<<2048, 256, 0, stream>>>(w_phi, w_theta, w_g, w_mask, wpt, wg, wm);
  transpose_x<<<dim3(64, 8, 4), 256, 0, stream>>>(x, xT);
  // PT[n, {phi|theta}] = xT @ wpt^T : M=4096, N=512, K=512, per batch
  gemm_bt<4096, 512, 512, true><<<dim3(4, 32, 4), 256, 0, stream>>>(
      xT, wpt, pt, 4096LL * 512, 0, 4096LL * 512);
  // g[c, n] = wg @ x : M=256, N=4096, K=512 (Bt = xT), per batch
  gemm_bt<256, 4096, 512, true><<<dim3(32, 2, 4), 256, 0, stream>>>(
      wg, xT, gB, 0, 4096LL * 512, 256LL * 4096);
  // flash attention v5: 256 blocks x 512 threads, in-block kv-split
  flash_attn3<<<dim3(256), 512, 0, stream>>>(pt, gB, yT);
  // out[o, n] = wm @ y : M=512, N=4096, K=256 (Bt = yT), fp32 out, per batch
  gemm_bt<512, 4096, 256, false><<<dim3(32, 4, 4), 256, 0, stream>>>(
      wm, yT, out, 0, 4096LL * 256, 512LL * 4096);
}

// Round 3
// 273.425 us; speedup vs baseline: 1.2953x; 1.0524x over previous
//
#include <hip/hip_runtime.h>

// SABlock: x(4,512,64,64) -> phi/theta/g (1x1 convs, CI=256) -> f=theta^T@phi
// -> softmax -> y=a@g^T -> w_mask 1x1 conv -> out(4,512,64,64)
// All GEMMs fp16-in / fp32-accumulate on MFMA 16x16x32_f16.
// Round 6: (a) XOR-swizzle Ps chunk placement -> kills the 8-way ds_write_b16
// bank conflict (was 1.9e7 conflict cycles ~ 31us of LDS pipe); (b) merged
// 32KB staging phases, 2-buffer ring, vmcnt(0)+barrier once per 32 MFMA
// (barriers/t-step 8 -> 4; less inter-group convoy). LDS = 160KB exactly.

#define BB 4
#define CC 512
#define NN_SP 4096   // H*W
#define CI 256

typedef _Float16 f16x8 __attribute__((ext_vector_type(8)));
typedef float f32x4 __attribute__((ext_vector_type(4)));

__device__ __forceinline__ void async16(const void* gsrc, void* ldst) {
  __builtin_amdgcn_global_load_lds(
      (const __attribute__((address_space(1))) unsigned int*)gsrc,
      (__attribute__((address_space(3))) unsigned int*)ldst, 16, 0, 0);
}

// ---------------- weight convert: fp32 -> f16, stack [w_phi; w_theta] ----------------
__global__ __launch_bounds__(256) void convert_w(
    const float* __restrict__ wphi, const float* __restrict__ wtheta,
    const float* __restrict__ wg, const float* __restrict__ wmask,
    _Float16* __restrict__ wpt, _Float16* __restrict__ wgh, _Float16* __restrict__ wmh) {
  int i = blockIdx.x * 256 + threadIdx.x;
  if (i < 512 * 512) {                       // wpt rows: 0..255 phi, 256..511 theta
    int row = i >> 9, k = i & 511;
    float v = (row < 256) ? wphi[row * 512 + k] : wtheta[(row - 256) * 512 + k];
    wpt[i] = (_Float16)v;
  } else if (i < 512 * 512 + 256 * 512) {
    int j = i - 512 * 512;
    wgh[j] = (_Float16)wg[j];
  } else {
    int j = i - 512 * 512 - 256 * 512;
    wmh[j] = (_Float16)wmask[j];
  }
}

// ---------------- x (B,512,4096) fp32 -> x_T (B,4096,512) f16 ----------------
__global__ __launch_bounds__(256) void transpose_x(const float* __restrict__ x,
                                                   _Float16* __restrict__ xT) {
  __shared__ float tile[64][65];   // +1 pad: conflict-free column read
  const int n0 = blockIdx.x * 64, c0 = blockIdx.y * 64, b = blockIdx.z;
  const int tx = threadIdx.x & 63, ty = threadIdx.x >> 6;
  const float* xb = x + (long long)b * CC * NN_SP;
#pragma unroll
  for (int i = 0; i < 16; ++i) {
    int row = i * 4 + ty;
    tile[row][tx] = xb[(long long)(c0 + row) * NN_SP + n0 + tx];
  }
  __syncthreads();
  _Float16* xTb = xT + (long long)b * NN_SP * CC;
#pragma unroll
  for (int i = 0; i < 16; ++i) {
    int row = i * 4 + ty;
    xTb[(long long)(n0 + row) * CC + c0 + tx] = (_Float16)tile[tx][row];
  }
}

// ---------------- generic gemm_bt: C[m,n] = sum_k A[m,k] * Bt[n,k] ----------------
// m97 structure: global_load_lds width-16 staging, 4 waves 2x2, 16 MFMA/wave/K-step.
template <int M, int NT, int K, bool F16OUT>
__global__ __launch_bounds__(256, 2) void gemm_bt(
    const _Float16* __restrict__ Ab, const _Float16* __restrict__ Btb,
    void* __restrict__ Cb, long long sA, long long sB, long long sC) {
  __shared__ _Float16 As[128 * 32];
  __shared__ _Float16 Bs[128 * 32];
  const int tid = threadIdx.x, lane = tid & 63, w = tid >> 6;
  const int wm = w >> 1, wn = w & 1;
  const int l15 = lane & 15, lq = lane >> 4;
  const int b = blockIdx.z;
  const _Float16* A = Ab + (long long)b * sA;
  const _Float16* Bt = Btb + (long long)b * sB;
  const int m0 = blockIdx.y * 128, n0 = blockIdx.x * 128;

  f32x4 acc[4][4];
#pragma unroll
  for (int i = 0; i < 4; ++i)
#pragma unroll
    for (int j = 0; j < 4; ++j) acc[i][j] = (f32x4){0.f, 0.f, 0.f, 0.f};

  for (int k0 = 0; k0 < K; k0 += 32) {
    __syncthreads();  // previous LDS reads done before overwrite
#pragma unroll
    for (int j = 0; j < 2; ++j) {
      int chw = j * 256 + w * 64;      // wave-uniform chunk base
      int ch = chw + lane;
      int row = ch >> 2, kc = ch & 3;  // 4 x 16B chunks per 32-k row segment
      async16(A + (long long)(m0 + row) * K + k0 + kc * 8, (void*)(As + chw * 8));
      async16(Bt + (long long)(n0 + row) * K + k0 + kc * 8, (void*)(Bs + chw * 8));
    }
    __syncthreads();  // vmcnt(0) drain + barrier
    f16x8 af[4], bf[4];
#pragma unroll
    for (int mt = 0; mt < 4; ++mt)
      af[mt] = *(const f16x8*)(As + (wm * 64 + mt * 16 + l15) * 32 + lq * 8);
#pragma unroll
    for (int nt = 0; nt < 4; ++nt)
      bf[nt] = *(const f16x8*)(Bs + (wn * 64 + nt * 16 + l15) * 32 + lq * 8);
#pragma unroll
    for (int mt = 0; mt < 4; ++mt)
#pragma unroll
      for (int nt = 0; nt < 4; ++nt)
        acc[mt][nt] = __builtin_amdgcn_mfma_f32_16x16x32_f16(af[mt], bf[nt], acc[mt][nt], 0, 0, 0);
  }

#pragma unroll
  for (int mt = 0; mt < 4; ++mt)
#pragma unroll
    for (int nt = 0; nt < 4; ++nt)
#pragma unroll
      for (int r = 0; r < 4; ++r) {
        int row = m0 + wm * 64 + mt * 16 + lq * 4 + r;  // C/D: row=(lane>>4)*4+reg
        int col = n0 + wn * 64 + nt * 16 + l15;         //      col=lane&15
        if (F16OUT)
          ((_Float16*)Cb + (long long)b * sC)[(long long)row * NT + col] = (_Float16)acc[mt][nt][r];
        else
          ((float*)Cb + (long long)b * sC)[(long long)row * NT + col] = acc[mt][nt][r];
      }
}

// ---------------- flash attention v6: in-block kv-split, merged phases ----------------
// pt (B,4096,512): cols 0..255 = phi_T, 256..511 = theta_T (c-contiguous)
// g  (B,256,4096): kv-contiguous.  yT (B,4096,256) f16 out.
// 256 blocks x 512 threads. Group hw=w>>2 owns kv half hw; wave wp=w&3 owns
// 16 q-rows. Per 128-kv t-step: 4 merged phases (2 phi, 2 g), each staging
// 32KB (two 16KB sub-chunks) into a 2-buffer ring. Sync per phase:
// s_waitcnt vmcnt(0) (own loads, issued a full phase earlier) + s_barrier.
// Ps chunk placement XOR-swizzled (u ^= (u>>3)&7): write spreads to 32 banks
// (was 8-way conflicted), read stays lane-contiguous-class conflict-free.
// End: group 1 dumps f32 partials to LDS, group 0 merges + stores.
__global__ __launch_bounds__(512, 2) void flash_attn3(
    const _Float16* __restrict__ pt, const _Float16* __restrict__ g,
    _Float16* __restrict__ yT) {
  __shared__ _Float16 Stg[2][2][16384];  // per-group 2 x 32KB ring (128KB)
  __shared__ _Float16 Ps[8][2048];       // per-wave P [16q][128kv] A-frag order (32KB)
  const int tid = threadIdx.x, lane = tid & 63, w = tid >> 6;
  const int hw = w >> 2, wp = w & 3;    // kv-half group, wave-in-group
  const int l15 = lane & 15, lq = lane >> 4;

  // XCD swizzle: 2 XCDs per batch -> per-XCD L2 working set = one batch's ~4MB
  const int idx = blockIdx.x;
  const int b = (idx >> 1) & 3;
  const int q0 = (((idx >> 3) << 1) | (idx & 1)) * 64;
  const int kvbase = hw * 2048;
  const _Float16* __restrict__ ptb = pt + (long long)b * NN_SP * 512;
  const _Float16* __restrict__ gb = g + (long long)b * CI * NN_SP;

  // Per-issue lane offsets (frag-order permutation), invariant over phases.
  // phi sub-chunk [128kv][64ch]: unit u -> (k2=u>>9, nv=(u>>6)&7, r15=(u>>2)&15, rq=u&3)
  //   src elem = (kv0 + nv*16 + r15)*512 + (c*64 + k2*32 + rq*8)
  // g sub-chunk [64c][128kv]: unit u -> (kq=u>>8, ct=(u>>6)&3, r15, rq)
  //   src elem = (c0 + ct*16 + r15)*4096 + (kv0 + kq*32 + rq*8)
  int offPhi[4], offG[4], chw_[4];
#pragma unroll
  for (int j = 0; j < 4; ++j) {
    int u = wp * 256 + j * 64 + lane;
    chw_[j] = wp * 256 + j * 64;
    int k2 = u >> 9, nv8 = (u >> 6) & 7, r15 = (u >> 2) & 15, rq = u & 3;
    offPhi[j] = (nv8 * 16 + r15) * 512 + k2 * 32 + rq * 8;
    int kq = u >> 8, ct4 = (u >> 6) & 3;
    offG[j] = (ct4 * 16 + r15) * 4096 + kq * 32 + rq * 8;
  }

  // Q (theta) resident in registers: 16 q-rows (shared with partner wave)
  f16x8 qreg[8];
#pragma unroll
  for (int kk = 0; kk < 8; ++kk)
    qreg[kk] = *(const f16x8*)(
        ptb + (long long)(q0 + wp * 16 + l15) * 512 + 256 + kk * 32 + lq * 8);

  f32x4 yacc[16];
#pragma unroll
  for (int nt = 0; nt < 16; ++nt) yacc[nt] = (f32x4){0.f, 0.f, 0.f, 0.f};
  float mrow[4] = {-3e38f, -3e38f, -3e38f, -3e38f};
  float lrow[4] = {0.f, 0.f, 0.f, 0.f};

  // issue merged phase mq (0..63) into this group's buffer bi:
  // two 16KB sub-chunks, 8 async16 per wave.
  auto issue = [&](int mq, int bi) {
    if (mq >= 64) return;            // 16 kv-steps x 4 merged phases per group
    int t = mq >> 2, mp = mq & 3, kv0 = kvbase + t * 128;
#pragma unroll
    for (int hh = 0; hh < 2; ++hh) {
      int sub = mp * 2 + hh;
      _Float16* buf = Stg[hw][bi] + hh * 8192;
      if (sub < 4) {
        const _Float16* basep = ptb + (long long)kv0 * 512 + sub * 64;
#pragma unroll
        for (int j = 0; j < 4; ++j)
          async16(basep + offPhi[j], (void*)(buf + chw_[j] * 8));
      } else {
        const _Float16* baseg = gb + (long long)(sub - 4) * 64 * 4096 + kv0;
#pragma unroll
        for (int j = 0; j < 4; ++j)
          async16(baseg + offG[j], (void*)(buf + chw_[j] * 8));
      }
    }
  };

  int p = 0;               // merged-phase counter; ring buffer = p & 1
  issue(0, 0);

  for (int t = 0; t < 16; ++t) {
    f32x4 S[8];
#pragma unroll
    for (int i = 0; i < 8; ++i) S[i] = (f32x4){0.f, 0.f, 0.f, 0.f};

    // ---- 2 merged phi phases: S = theta @ phi^T ----
#pragma unroll
    for (int mp = 0; mp < 2; ++mp) {
      asm volatile("s_waitcnt vmcnt(0)" ::: "memory");  // own loads for phase p done
      asm volatile("s_barrier" ::: "memory");           // all waves: data in, other buf free
      issue(p + 1, (p + 1) & 1);
      const _Float16* bufb = Stg[hw][p & 1];
#pragma unroll
      for (int hh = 0; hh < 2; ++hh) {
        int c = mp * 2 + hh;
        const _Float16* buf = bufb + hh * 8192;
#pragma unroll
        for (int k2 = 0; k2 < 2; ++k2)
#pragma unroll
          for (int nv = 0; nv < 8; ++nv) {
            f16x8 bf = *(const f16x8*)(buf + (k2 * 512 + nv * 64 + l15 * 4 + lq) * 8);
            S[nv] = __builtin_amdgcn_mfma_f32_16x16x32_f16(qreg[c * 2 + k2], bf, S[nv], 0, 0, 0);
          }
      }
      ++p;
    }

    // ---- wave-private online softmax (rows = lq*4+r, cols across l15) ----
    float alpha[4];
#pragma unroll
    for (int r = 0; r < 4; ++r) {
      float mx = fmaxf(fmaxf(S[0][r], S[1][r]), fmaxf(S[2][r], S[3][r]));
      mx = fmaxf(mx, fmaxf(fmaxf(S[4][r], S[5][r]), fmaxf(S[6][r], S[7][r])));
#pragma unroll
      for (int d = 1; d < 16; d <<= 1) mx = fmaxf(mx, __shfl_xor(mx, d, 64));
      float nm = fmaxf(mrow[r], mx);
      alpha[r] = __expf(mrow[r] - nm);
      mrow[r] = nm;
      float ps = 0.f;
#pragma unroll
      for (int nv = 0; nv < 8; ++nv) {
        float pv = __expf(S[nv][r] - nm);
        S[nv][r] = pv;
        ps += pv;
      }
#pragma unroll
      for (int d = 1; d < 16; d <<= 1) ps += __shfl_xor(ps, d, 64);
      lrow[r] = lrow[r] * alpha[r] + ps;
    }
    {
      f32x4 al = {alpha[0], alpha[1], alpha[2], alpha[3]};
#pragma unroll
      for (int nt = 0; nt < 16; ++nt) yacc[nt] *= al;
    }

    // ---- P: C/D regs -> wave-private LDS, XOR-swizzled chunks ----
    // write banks: chunk' mod 8 = CH[2:0]^CH[5:3] sweeps 8 values across
    // (lq, l15>>3) per instruction -> 32 banks (was 8-way conflict).
#pragma unroll
    for (int nv = 0; nv < 8; ++nv) {
      int kq = nv >> 1;
      int lqr = (nv & 1) * 2 + (l15 >> 3);
      int e = l15 & 7;
#pragma unroll
      for (int r = 0; r < 4; ++r) {
        int u = kq * 64 + lqr * 16 + lq * 4 + r;
        int us = u ^ ((u >> 3) & 7);
        Ps[w][us * 8 + e] = (_Float16)S[nv][r];
      }
    }
    f16x8 aP[4];
#pragma unroll
    for (int kq = 0; kq < 4; ++kq) {
      int ur = kq * 64 + lane;
      int urs = ur ^ ((ur >> 3) & 7);
      aP[kq] = *(const f16x8*)(&Ps[w][urs * 8]);
    }

    // ---- 2 merged g phases: y += P @ g^T ----
#pragma unroll
    for (int mp = 0; mp < 2; ++mp) {
      asm volatile("s_waitcnt vmcnt(0)" ::: "memory");
      asm volatile("s_barrier" ::: "memory");
      issue(p + 1, (p + 1) & 1);
      const _Float16* bufb = Stg[hw][p & 1];
#pragma unroll
      for (int hh = 0; hh < 2; ++hh) {
        int cg = mp * 2 + hh;
        const _Float16* buf = bufb + hh * 8192;
#pragma unroll
        for (int kq = 0; kq < 4; ++kq)
#pragma unroll
          for (int ct = 0; ct < 4; ++ct) {
            f16x8 bf = *(const f16x8*)(buf + (kq * 256 + ct * 64 + l15 * 4 + lq) * 8);
            yacc[cg * 4 + ct] =
                __builtin_amdgcn_mfma_f32_16x16x32_f16(aP[kq], bf, yacc[cg * 4 + ct], 0, 0, 0);
          }
      }
      ++p;
    }
  }

  // ---- in-block f32 merge: group 1 -> LDS, group 0 combines + stores ----
  __syncthreads();  // all waves done with Stg before it is reused
  float* mbuf = (float*)Stg;                    // [64 rows][stride 257] f32 (~66KB)
  float* sbuf = (float*)((char*)Stg + 81920);   // [64 rows][2] f32 (m,l)
  if (hw == 1) {
#pragma unroll
    for (int r = 0; r < 4; ++r) {
      int rr = wp * 16 + lq * 4 + r;
#pragma unroll
      for (int nt = 0; nt < 16; ++nt)
        mbuf[rr * 257 + nt * 16 + l15] = yacc[nt][r];
      if (l15 == 0) {
        sbuf[rr * 2 + 0] = mrow[r];
        sbuf[rr * 2 + 1] = lrow[r];
      }
    }
  }
  __syncthreads();
  if (hw == 0) {
    _Float16* yTb = yT + (long long)b * NN_SP * CI;
#pragma unroll
    for (int r = 0; r < 4; ++r) {
      int rr = wp * 16 + lq * 4 + r;
      float m2 = sbuf[rr * 2 + 0], l2 = sbuf[rr * 2 + 1];
      float m = fmaxf(mrow[r], m2);
      float w1 = __expf(mrow[r] - m), w2 = __expf(m2 - m);
      float inv = 1.f / (w1 * lrow[r] + w2 * l2);
      int row = q0 + rr;
#pragma unroll
      for (int nt = 0; nt < 16; ++nt) {
        float v2 = mbuf[rr * 257 + nt * 16 + l15];
        yTb[(long long)row * CI + nt * 16 + l15] =
            (_Float16)((w1 * yacc[nt][r] + w2 * v2) * inv);
      }
    }
  }
}

extern "C" void kernel_launch(void* const* d_in, const int* in_sizes, int n_in,
                              void* d_out, int out_size, void* d_ws, size_t ws_size,
                              hipStream_t stream) {
  const float* x = (const float*)d_in[0];
  const float* w_phi = (const float*)d_in[1];
  const float* w_theta = (const float*)d_in[2];
  const float* w_g = (const float*)d_in[3];
  const float* w_mask = (const float*)d_in[4];
  float* out = (float*)d_out;
  char* ws = (char*)d_ws;

  // workspace layout (51.4 MB total)
  _Float16* xT = (_Float16*)(ws);                 // (B,4096,512)  16.78 MB
  _Float16* pt = (_Float16*)(ws + 16777216);      // (B,4096,512)  16.78 MB  [phi|theta]
  _Float16* gB = (_Float16*)(ws + 33554432);      // (B,256,4096)   8.39 MB
  _Float16* yT = (_Float16*)(ws + 41943040);      // (B,4096,256)   8.39 MB
  _Float16* wpt = (_Float16*)(ws + 50331648);     // (512,512)
  _Float16* wg = (_Float16*)(ws + 50855936);      // (256,512)
  _Float16* wm = (_Float16*)(ws + 51118080);      // (512,256)

  convert_w<<<2048, 256, 0, stream>>>(w_phi, w_theta, w_g, w_mask, wpt, wg, wm);
  transpose_x<<<dim3(64, 8, 4), 256, 0, stream>>>(x, xT);
  // PT[n, {phi|theta}] = xT @ wpt^T : M=4096, N=512, K=512, per batch
  gemm_bt<4096, 512, 512, true><<<dim3(4, 32, 4), 256, 0, stream>>>(
      xT, wpt, pt, 4096LL * 512, 0, 4096LL * 512);
  // g[c, n] = wg @ x : M=256, N=4096, K=512 (Bt = xT), per batch
  gemm_bt<256, 4096, 512, true><<<dim3(32, 2, 4), 256, 0, stream>>>(
      wg, xT, gB, 0, 4096LL * 512, 256LL * 4096);
  // flash attention v6: 256 blocks x 512 threads, in-block kv-split, merged phases
  flash_attn3<<<dim3(256), 512, 0, stream>>>(pt, gB, yT);
  // out[o, n] = wm @ y : M=512, N=4096, K=256 (Bt = yT), fp32 out, per batch
  gemm_bt<512, 4096, 256, false><<<dim3(32, 4, 4), 256, 0, stream>>>(
      wm, yT, out, 0, 4096LL * 256, 512LL * 4096);
}

// Round 4
// 252.068 us; speedup vs baseline: 1.4050x; 1.0847x over previous
//
#include <hip/hip_runtime.h>

// SABlock: x(4,512,64,64) -> phi/theta/g (1x1 convs, CI=256) -> f=theta^T@phi
// -> softmax -> y=a@g^T -> w_mask 1x1 conv -> out(4,512,64,64)
// All GEMMs fp16-in / fp32-accumulate on MFMA 16x16x32_f16.
// Round 7: chunk-XOR swizzle (c ^= (c>>3)&7) on the STAGING buffers — the
// B-frag ds_read_b128 index (l15*4+lq) put quarter-wave lanes on 8 banks
// (8-way conflict, ~1.6e7 cycles = the dominant SQ_LDS_BANK_CONFLICT source).
// LDS image stays linear; the global source permutation absorbs the swizzle
// (m173), reads use the XOR'd index. + s_setprio(1) around MFMA clusters.

#define BB 4
#define CC 512
#define NN_SP 4096   // H*W
#define CI 256

typedef _Float16 f16x8 __attribute__((ext_vector_type(8)));
typedef float f32x4 __attribute__((ext_vector_type(4)));

__device__ __forceinline__ void async16(const void* gsrc, void* ldst) {
  __builtin_amdgcn_global_load_lds(
      (const __attribute__((address_space(1))) unsigned int*)gsrc,
      (__attribute__((address_space(3))) unsigned int*)ldst, 16, 0, 0);
}

// ---------------- weight convert: fp32 -> f16, stack [w_phi; w_theta] ----------------
__global__ __launch_bounds__(256) void convert_w(
    const float* __restrict__ wphi, const float* __restrict__ wtheta,
    const float* __restrict__ wg, const float* __restrict__ wmask,
    _Float16* __restrict__ wpt, _Float16* __restrict__ wgh, _Float16* __restrict__ wmh) {
  int i = blockIdx.x * 256 + threadIdx.x;
  if (i < 512 * 512) {                       // wpt rows: 0..255 phi, 256..511 theta
    int row = i >> 9, k = i & 511;
    float v = (row < 256) ? wphi[row * 512 + k] : wtheta[(row - 256) * 512 + k];
    wpt[i] = (_Float16)v;
  } else if (i < 512 * 512 + 256 * 512) {
    int j = i - 512 * 512;
    wgh[j] = (_Float16)wg[j];
  } else {
    int j = i - 512 * 512 - 256 * 512;
    wmh[j] = (_Float16)wmask[j];
  }
}

// ---------------- x (B,512,4096) fp32 -> x_T (B,4096,512) f16 ----------------
__global__ __launch_bounds__(256) void transpose_x(const float* __restrict__ x,
                                                   _Float16* __restrict__ xT) {
  __shared__ float tile[64][65];   // +1 pad: conflict-free column read
  const int n0 = blockIdx.x * 64, c0 = blockIdx.y * 64, b = blockIdx.z;
  const int tx = threadIdx.x & 63, ty = threadIdx.x >> 6;
  const float* xb = x + (long long)b * CC * NN_SP;
#pragma unroll
  for (int i = 0; i < 16; ++i) {
    int row = i * 4 + ty;
    tile[row][tx] = xb[(long long)(c0 + row) * NN_SP + n0 + tx];
  }
  __syncthreads();
  _Float16* xTb = xT + (long long)b * NN_SP * CC;
#pragma unroll
  for (int i = 0; i < 16; ++i) {
    int row = i * 4 + ty;
    xTb[(long long)(n0 + row) * CC + c0 + tx] = (_Float16)tile[tx][row];
  }
}

// ---------------- generic gemm_bt: C[m,n] = sum_k A[m,k] * Bt[n,k] ----------------
// m97 structure: global_load_lds width-16 staging, 4 waves 2x2, 16 MFMA/wave/K-step.
template <int M, int NT, int K, bool F16OUT>
__global__ __launch_bounds__(256, 2) void gemm_bt(
    const _Float16* __restrict__ Ab, const _Float16* __restrict__ Btb,
    void* __restrict__ Cb, long long sA, long long sB, long long sC) {
  __shared__ _Float16 As[128 * 32];
  __shared__ _Float16 Bs[128 * 32];
  const int tid = threadIdx.x, lane = tid & 63, w = tid >> 6;
  const int wm = w >> 1, wn = w & 1;
  const int l15 = lane & 15, lq = lane >> 4;
  const int b = blockIdx.z;
  const _Float16* A = Ab + (long long)b * sA;
  const _Float16* Bt = Btb + (long long)b * sB;
  const int m0 = blockIdx.y * 128, n0 = blockIdx.x * 128;

  f32x4 acc[4][4];
#pragma unroll
  for (int i = 0; i < 4; ++i)
#pragma unroll
    for (int j = 0; j < 4; ++j) acc[i][j] = (f32x4){0.f, 0.f, 0.f, 0.f};

  for (int k0 = 0; k0 < K; k0 += 32) {
    __syncthreads();  // previous LDS reads done before overwrite
#pragma unroll
    for (int j = 0; j < 2; ++j) {
      int chw = j * 256 + w * 64;      // wave-uniform chunk base
      int ch = chw + lane;
      int row = ch >> 2, kc = ch & 3;  // 4 x 16B chunks per 32-k row segment
      async16(A + (long long)(m0 + row) * K + k0 + kc * 8, (void*)(As + chw * 8));
      async16(Bt + (long long)(n0 + row) * K + k0 + kc * 8, (void*)(Bs + chw * 8));
    }
    __syncthreads();  // vmcnt(0) drain + barrier
    f16x8 af[4], bf[4];
#pragma unroll
    for (int mt = 0; mt < 4; ++mt)
      af[mt] = *(const f16x8*)(As + (wm * 64 + mt * 16 + l15) * 32 + lq * 8);
#pragma unroll
    for (int nt = 0; nt < 4; ++nt)
      bf[nt] = *(const f16x8*)(Bs + (wn * 64 + nt * 16 + l15) * 32 + lq * 8);
#pragma unroll
    for (int mt = 0; mt < 4; ++mt)
#pragma unroll
      for (int nt = 0; nt < 4; ++nt)
        acc[mt][nt] = __builtin_amdgcn_mfma_f32_16x16x32_f16(af[mt], bf[nt], acc[mt][nt], 0, 0, 0);
  }

#pragma unroll
  for (int mt = 0; mt < 4; ++mt)
#pragma unroll
    for (int nt = 0; nt < 4; ++nt)
#pragma unroll
      for (int r = 0; r < 4; ++r) {
        int row = m0 + wm * 64 + mt * 16 + lq * 4 + r;  // C/D: row=(lane>>4)*4+reg
        int col = n0 + wn * 64 + nt * 16 + l15;         //      col=lane&15
        if (F16OUT)
          ((_Float16*)Cb + (long long)b * sC)[(long long)row * NT + col] = (_Float16)acc[mt][nt][r];
        else
          ((float*)Cb + (long long)b * sC)[(long long)row * NT + col] = acc[mt][nt][r];
      }
}

// ---------------- flash attention v7: swizzled staging ----------------
// pt (B,4096,512): cols 0..255 = phi_T, 256..511 = theta_T (c-contiguous)
// g  (B,256,4096): kv-contiguous.  yT (B,4096,256) f16 out.
// 256 blocks x 512 threads. Group hw=w>>2 owns kv half hw; wave wp=w&3 owns
// 16 q-rows. Per 128-kv t-step: 4 merged phases (2 phi, 2 g), 32KB each into
// a 2-buffer ring; vmcnt(0)+s_barrier per phase.
// Chunk-XOR swizzle c ^= (c>>3)&7 (involution, within 64-chunk groups):
// staging source permutation pre-applies it (LDS dest stays linear, as
// global_load_lds requires); frag reads use the XOR'd index -> quarter-wave
// lanes spread over all 8 bank-groups (2-way same-group = free) instead of
// the linear layout's 8-way conflict. Same swizzle on Ps (r3).
__global__ __launch_bounds__(512, 2) void flash_attn3(
    const _Float16* __restrict__ pt, const _Float16* __restrict__ g,
    _Float16* __restrict__ yT) {
  __shared__ _Float16 Stg[2][2][16384];  // per-group 2 x 32KB ring (128KB)
  __shared__ _Float16 Ps[8][2048];       // per-wave P [16q][128kv] A-frag order (32KB)
  const int tid = threadIdx.x, lane = tid & 63, w = tid >> 6;
  const int hw = w >> 2, wp = w & 3;    // kv-half group, wave-in-group
  const int l15 = lane & 15, lq = lane >> 4;

  // XCD swizzle: 2 XCDs per batch -> per-XCD L2 working set = one batch's ~4MB
  const int idx = blockIdx.x;
  const int b = (idx >> 1) & 3;
  const int q0 = (((idx >> 3) << 1) | (idx & 1)) * 64;
  const int kvbase = hw * 2048;
  const _Float16* __restrict__ ptb = pt + (long long)b * NN_SP * 512;
  const _Float16* __restrict__ gb = g + (long long)b * CI * NN_SP;

  // Per-issue lane offsets (frag-order permutation + chunk-XOR), invariant.
  // LDS chunk u holds the data of frag-index us = u ^ ((u>>3)&7); the reader
  // addresses chunk (r ^ ((r>>3)&7)) for frag r (involution: bits 5:3 fixed).
  // phi sub-chunk: frag us -> (k2=us>>9, nv=(us>>6)&7, r15=(us>>2)&15, rq=us&3)
  //   src elem = (kv0 + nv*16 + r15)*512 + (c*64 + k2*32 + rq*8)
  // g sub-chunk: frag us -> (kq=us>>8, ct=(us>>6)&3, r15, rq)
  //   src elem = (c0 + ct*16 + r15)*4096 + (kv0 + kq*32 + rq*8)
  int offPhi[4], offG[4], chw_[4];
#pragma unroll
  for (int j = 0; j < 4; ++j) {
    int u = wp * 256 + j * 64 + lane;
    chw_[j] = wp * 256 + j * 64;
    int us = u ^ ((u >> 3) & 7);   // chunk-XOR: this LDS chunk holds frag 'us'
    int k2 = us >> 9, nv8 = (us >> 6) & 7, r15 = (us >> 2) & 15, rq = us & 3;
    offPhi[j] = (nv8 * 16 + r15) * 512 + k2 * 32 + rq * 8;
    int kq = us >> 8, ct4 = (us >> 6) & 3;
    offG[j] = (ct4 * 16 + r15) * 4096 + kq * 32 + rq * 8;
  }
  // swizzled read index for frag (l15*4+lq) within each 64-chunk group
  const int rswz = (l15 * 4 + lq) ^ ((l15 >> 1) & 7);

  // Q (theta) resident in registers: 16 q-rows (shared with partner wave)
  f16x8 qreg[8];
#pragma unroll
  for (int kk = 0; kk < 8; ++kk)
    qreg[kk] = *(const f16x8*)(
        ptb + (long long)(q0 + wp * 16 + l15) * 512 + 256 + kk * 32 + lq * 8);

  f32x4 yacc[16];
#pragma unroll
  for (int nt = 0; nt < 16; ++nt) yacc[nt] = (f32x4){0.f, 0.f, 0.f, 0.f};
  float mrow[4] = {-3e38f, -3e38f, -3e38f, -3e38f};
  float lrow[4] = {0.f, 0.f, 0.f, 0.f};

  // issue merged phase mq (0..63) into this group's buffer bi:
  // two 16KB sub-chunks, 8 async16 per wave.
  auto issue = [&](int mq, int bi) {
    if (mq >= 64) return;            // 16 kv-steps x 4 merged phases per group
    int t = mq >> 2, mp = mq & 3, kv0 = kvbase + t * 128;
#pragma unroll
    for (int hh = 0; hh < 2; ++hh) {
      int sub = mp * 2 + hh;
      _Float16* buf = Stg[hw][bi] + hh * 8192;
      if (sub < 4) {
        const _Float16* basep = ptb + (long long)kv0 * 512 + sub * 64;
#pragma unroll
        for (int j = 0; j < 4; ++j)
          async16(basep + offPhi[j], (void*)(buf + chw_[j] * 8));
      } else {
        const _Float16* baseg = gb + (long long)(sub - 4) * 64 * 4096 + kv0;
#pragma unroll
        for (int j = 0; j < 4; ++j)
          async16(baseg + offG[j], (void*)(buf + chw_[j] * 8));
      }
    }
  };

  int p = 0;               // merged-phase counter; ring buffer = p & 1
  issue(0, 0);

  for (int t = 0; t < 16; ++t) {
    f32x4 S[8];
#pragma unroll
    for (int i = 0; i < 8; ++i) S[i] = (f32x4){0.f, 0.f, 0.f, 0.f};

    // ---- 2 merged phi phases: S = theta @ phi^T ----
#pragma unroll
    for (int mp = 0; mp < 2; ++mp) {
      asm volatile("s_waitcnt vmcnt(0)" ::: "memory");  // own loads for phase p done
      asm volatile("s_barrier" ::: "memory");           // all waves: data in, other buf free
      issue(p + 1, (p + 1) & 1);
      const _Float16* bufb = Stg[hw][p & 1];
      __builtin_amdgcn_s_setprio(1);
#pragma unroll
      for (int hh = 0; hh < 2; ++hh) {
        int c = mp * 2 + hh;
        const _Float16* buf = bufb + hh * 8192;
#pragma unroll
        for (int k2 = 0; k2 < 2; ++k2)
#pragma unroll
          for (int nv = 0; nv < 8; ++nv) {
            f16x8 bf = *(const f16x8*)(buf + (k2 * 512 + nv * 64 + rswz) * 8);
            S[nv] = __builtin_amdgcn_mfma_f32_16x16x32_f16(qreg[c * 2 + k2], bf, S[nv], 0, 0, 0);
          }
      }
      __builtin_amdgcn_s_setprio(0);
      ++p;
    }

    // ---- wave-private online softmax (rows = lq*4+r, cols across l15) ----
    float alpha[4];
#pragma unroll
    for (int r = 0; r < 4; ++r) {
      float mx = fmaxf(fmaxf(S[0][r], S[1][r]), fmaxf(S[2][r], S[3][r]));
      mx = fmaxf(mx, fmaxf(fmaxf(S[4][r], S[5][r]), fmaxf(S[6][r], S[7][r])));
#pragma unroll
      for (int d = 1; d < 16; d <<= 1) mx = fmaxf(mx, __shfl_xor(mx, d, 64));
      float nm = fmaxf(mrow[r], mx);
      alpha[r] = __expf(mrow[r] - nm);
      mrow[r] = nm;
      float ps = 0.f;
#pragma unroll
      for (int nv = 0; nv < 8; ++nv) {
        float pv = __expf(S[nv][r] - nm);
        S[nv][r] = pv;
        ps += pv;
      }
#pragma unroll
      for (int d = 1; d < 16; d <<= 1) ps += __shfl_xor(ps, d, 64);
      lrow[r] = lrow[r] * alpha[r] + ps;
    }
    {
      f32x4 al = {alpha[0], alpha[1], alpha[2], alpha[3]};
#pragma unroll
      for (int nt = 0; nt < 16; ++nt) yacc[nt] *= al;
    }

    // ---- P: C/D regs -> wave-private LDS, XOR-swizzled chunks (r3) ----
#pragma unroll
    for (int nv = 0; nv < 8; ++nv) {
      int kq = nv >> 1;
      int lqr = (nv & 1) * 2 + (l15 >> 3);
      int e = l15 & 7;
#pragma unroll
      for (int r = 0; r < 4; ++r) {
        int u = kq * 64 + lqr * 16 + lq * 4 + r;
        int us = u ^ ((u >> 3) & 7);
        Ps[w][us * 8 + e] = (_Float16)S[nv][r];
      }
    }
    f16x8 aP[4];
#pragma unroll
    for (int kq = 0; kq < 4; ++kq) {
      int ur = kq * 64 + lane;
      int urs = ur ^ ((ur >> 3) & 7);
      aP[kq] = *(const f16x8*)(&Ps[w][urs * 8]);
    }

    // ---- 2 merged g phases: y += P @ g^T ----
#pragma unroll
    for (int mp = 0; mp < 2; ++mp) {
      if (t == 15 && mp == 1) {
        asm volatile("s_waitcnt vmcnt(0)" ::: "memory");
      } else {
        asm volatile("s_waitcnt vmcnt(0)" ::: "memory");
      }
      asm volatile("s_barrier" ::: "memory");
      issue(p + 1, (p + 1) & 1);
      const _Float16* bufb = Stg[hw][p & 1];
      __builtin_amdgcn_s_setprio(1);
#pragma unroll
      for (int hh = 0; hh < 2; ++hh) {
        int cg = mp * 2 + hh;
        const _Float16* buf = bufb + hh * 8192;
#pragma unroll
        for (int kq = 0; kq < 4; ++kq)
#pragma unroll
          for (int ct = 0; ct < 4; ++ct) {
            f16x8 bf = *(const f16x8*)(buf + (kq * 256 + ct * 64 + rswz) * 8);
            yacc[cg * 4 + ct] =
                __builtin_amdgcn_mfma_f32_16x16x32_f16(aP[kq], bf, yacc[cg * 4 + ct], 0, 0, 0);
          }
      }
      __builtin_amdgcn_s_setprio(0);
      ++p;
    }
  }

  // ---- in-block f32 merge: group 1 -> LDS, group 0 combines + stores ----
  __syncthreads();  // all waves done with Stg before it is reused
  float* mbuf = (float*)Stg;                    // [64 rows][stride 257] f32 (~66KB)
  float* sbuf = (float*)((char*)Stg + 81920);   // [64 rows][2] f32 (m,l)
  if (hw == 1) {
#pragma unroll
    for (int r = 0; r < 4; ++r) {
      int rr = wp * 16 + lq * 4 + r;
#pragma unroll
      for (int nt = 0; nt < 16; ++nt)
        mbuf[rr * 257 + nt * 16 + l15] = yacc[nt][r];
      if (l15 == 0) {
        sbuf[rr * 2 + 0] = mrow[r];
        sbuf[rr * 2 + 1] = lrow[r];
      }
    }
  }
  __syncthreads();
  if (hw == 0) {
    _Float16* yTb = yT + (long long)b * NN_SP * CI;
#pragma unroll
    for (int r = 0; r < 4; ++r) {
      int rr = wp * 16 + lq * 4 + r;
      float m2 = sbuf[rr * 2 + 0], l2 = sbuf[rr * 2 + 1];
      float m = fmaxf(mrow[r], m2);
      float w1 = __expf(mrow[r] - m), w2 = __expf(m2 - m);
      float inv = 1.f / (w1 * lrow[r] + w2 * l2);
      int row = q0 + rr;
#pragma unroll
      for (int nt = 0; nt < 16; ++nt) {
        float v2 = mbuf[rr * 257 + nt * 16 + l15];
        yTb[(long long)row * CI + nt * 16 + l15] =
            (_Float16)((w1 * yacc[nt][r] + w2 * v2) * inv);
      }
    }
  }
}

extern "C" void kernel_launch(void* const* d_in, const int* in_sizes, int n_in,
                              void* d_out, int out_size, void* d_ws, size_t ws_size,
                              hipStream_t stream) {
  const float* x = (const float*)d_in[0];
  const float* w_phi = (const float*)d_in[1];
  const float* w_theta = (const float*)d_in[2];
  const float* w_g = (const float*)d_in[3];
  const float* w_mask = (const float*)d_in[4];
  float* out = (float*)d_out;
  char* ws = (char*)d_ws;

  // workspace layout (51.4 MB total)
  _Float16* xT = (_Float16*)(ws);                 // (B,4096,512)  16.78 MB
  _Float16* pt = (_Float16*)(ws + 16777216);      // (B,4096,512)  16.78 MB  [phi|theta]
  _Float16* gB = (_Float16*)(ws + 33554432);      // (B,256,4096)   8.39 MB
  _Float16* yT = (_Float16*)(ws + 41943040);      // (B,4096,256)   8.39 MB
  _Float16* wpt = (_Float16*)(ws + 50331648);     // (512,512)
  _Float16* wg = (_Float16*)(ws + 50855936);      // (256,512)
  _Float16* wm = (_Float16*)(ws + 51118080);      // (512,256)

  convert_w<<<2048, 256, 0, stream>>>(w_phi, w_theta, w_g, w_mask, wpt, wg, wm);
  transpose_x<<<dim3(64, 8, 4), 256, 0, stream>>>(x, xT);
  // PT[n, {phi|theta}] = xT @ wpt^T : M=4096, N=512, K=512, per batch
  gemm_bt<4096, 512, 512, true><<<dim3(4, 32, 4), 256, 0, stream>>>(
      xT, wpt, pt, 4096LL * 512, 0, 4096LL * 512);
  // g[c, n] = wg @ x : M=256, N=4096, K=512 (Bt = xT), per batch
  gemm_bt<256, 4096, 512, true><<<dim3(32, 2, 4), 256, 0, stream>>>(
      wg, xT, gB, 0, 4096LL * 512, 256LL * 4096);
  // flash attention v7: 256 blocks x 512 threads, swizzled staging
  flash_attn3<<<dim3(256), 512, 0, stream>>>(pt, gB, yT);
  // out[o, n] = wm @ y : M=512, N=4096, K=256 (Bt = yT), fp32 out, per batch
  gemm_bt<512, 4096, 256, false><<<dim3(32, 4, 4), 256, 0, stream>>>(
      wm, yT, out, 0, 4096LL * 256, 512LL * 4096);
}

// Round 5
// 240.691 us; speedup vs baseline: 1.4714x; 1.0473x over previous
//
#include <hip/hip_runtime.h>

// SABlock: x(4,512,64,64) -> phi/theta/g (1x1 convs, CI=256) -> f=theta^T@phi
// -> softmax -> y=a@g^T -> w_mask 1x1 conv -> out(4,512,64,64)
// All GEMMs fp16-in / fp32-accumulate on MFMA 16x16x32_f16.
// Round 8: (a) flash softmax row-sum via MFMA (lacc += P@1, C/D layout match)
// replacing the 4-shfl sum-butterfly; exact skip-rescale via __ballot (alpha==1
// when no row max grew). (b) GEMMs: BK=64 (half the barriers) + chunk-XOR
// swizzle (BK=64 linear would be a 16-way frag-read conflict). (c) transpose_x
// packed u32 f16x2 stores.

#define BB 4
#define CC 512
#define NN_SP 4096   // H*W
#define CI 256

typedef _Float16 f16x8 __attribute__((ext_vector_type(8)));
typedef float f32x4 __attribute__((ext_vector_type(4)));

__device__ __forceinline__ void async16(const void* gsrc, void* ldst) {
  __builtin_amdgcn_global_load_lds(
      (const __attribute__((address_space(1))) unsigned int*)gsrc,
      (__attribute__((address_space(3))) unsigned int*)ldst, 16, 0, 0);
}

// ---------------- weight convert: fp32 -> f16, stack [w_phi; w_theta] ----------------
__global__ __launch_bounds__(256) void convert_w(
    const float* __restrict__ wphi, const float* __restrict__ wtheta,
    const float* __restrict__ wg, const float* __restrict__ wmask,
    _Float16* __restrict__ wpt, _Float16* __restrict__ wgh, _Float16* __restrict__ wmh) {
  int i = blockIdx.x * 256 + threadIdx.x;
  if (i < 512 * 512) {                       // wpt rows: 0..255 phi, 256..511 theta
    int row = i >> 9, k = i & 511;
    float v = (row < 256) ? wphi[row * 512 + k] : wtheta[(row - 256) * 512 + k];
    wpt[i] = (_Float16)v;
  } else if (i < 512 * 512 + 256 * 512) {
    int j = i - 512 * 512;
    wgh[j] = (_Float16)wg[j];
  } else {
    int j = i - 512 * 512 - 256 * 512;
    wmh[j] = (_Float16)wmask[j];
  }
}

// ---------------- x (B,512,4096) fp32 -> x_T (B,4096,512) f16 ----------------
__global__ __launch_bounds__(256) void transpose_x(const float* __restrict__ x,
                                                   _Float16* __restrict__ xT) {
  __shared__ float tile[64][65];   // +1 pad: conflict-free column read
  const int n0 = blockIdx.x * 64, c0 = blockIdx.y * 64, b = blockIdx.z;
  const int tx = threadIdx.x & 63, ty = threadIdx.x >> 6;
  const float* xb = x + (long long)b * CC * NN_SP;
#pragma unroll
  for (int i = 0; i < 16; ++i) {
    int row = i * 4 + ty;
    tile[row][tx] = xb[(long long)(c0 + row) * NN_SP + n0 + tx];
  }
  __syncthreads();
  // write: 2 consecutive c per lane packed into one u32 store (4B/lane)
  const int cx = threadIdx.x & 31;   // c-pair index
  const int ny = threadIdx.x >> 5;   // 0..7
  _Float16* xTb = xT + (long long)b * NN_SP * CC;
#pragma unroll
  for (int i = 0; i < 8; ++i) {
    int n = i * 8 + ny;
    union { _Float16 h[2]; unsigned int u; } pk;
    pk.h[0] = (_Float16)tile[cx * 2][n];
    pk.h[1] = (_Float16)tile[cx * 2 + 1][n];
    *(unsigned int*)(xTb + (long long)(n0 + n) * CC + c0 + cx * 2) = pk.u;
  }
}

// ---------------- generic gemm_bt: C[m,n] = sum_k A[m,k] * Bt[n,k] ----------------
// m97-derived: global_load_lds width-16 staging, 4 waves 2x2, BK=64 (2 k-halves
// per barrier pair), chunk-XOR swizzled LDS image (linear BK=64 frag reads
// would be 16-way bank-conflicted: row stride 128B = bank wrap).
template <int M, int NT, int K, bool F16OUT>
__global__ __launch_bounds__(256, 2) void gemm_bt(
    const _Float16* __restrict__ Ab, const _Float16* __restrict__ Btb,
    void* __restrict__ Cb, long long sA, long long sB, long long sC) {
  __shared__ _Float16 As[128 * 64];   // 16KB
  __shared__ _Float16 Bs[128 * 64];   // 16KB
  const int tid = threadIdx.x, lane = tid & 63, w = tid >> 6;
  const int wm = w >> 1, wn = w & 1;
  const int l15 = lane & 15, lq = lane >> 4;
  const int b = blockIdx.z;
  const _Float16* A = Ab + (long long)b * sA;
  const _Float16* Bt = Btb + (long long)b * sB;
  const int m0 = blockIdx.y * 128, n0 = blockIdx.x * 128;

  f32x4 acc[4][4];
#pragma unroll
  for (int i = 0; i < 4; ++i)
#pragma unroll
    for (int j = 0; j < 4; ++j) acc[i][j] = (f32x4){0.f, 0.f, 0.f, 0.f};

  for (int k0 = 0; k0 < K; k0 += 64) {
    __syncthreads();  // previous LDS reads done before overwrite
#pragma unroll
    for (int j = 0; j < 4; ++j) {
      int chw = j * 256 + w * 64;          // wave-uniform chunk base
      int ch = chw + lane;
      int us = ch ^ ((ch >> 3) & 7);       // this LDS chunk holds frag-chunk us
      int row = us >> 3, kc = us & 7;      // 8 x 16B chunks per 64-k row
      async16(A + (long long)(m0 + row) * K + k0 + kc * 8, (void*)(As + chw * 8));
      async16(Bt + (long long)(n0 + row) * K + k0 + kc * 8, (void*)(Bs + chw * 8));
    }
    __syncthreads();  // vmcnt(0) drain + barrier
#pragma unroll
    for (int kh = 0; kh < 2; ++kh) {
      f16x8 af[4], bf[4];
#pragma unroll
      for (int mt = 0; mt < 4; ++mt) {
        int c = (wm * 64 + mt * 16 + l15) * 8 + kh * 4 + lq;
        af[mt] = *(const f16x8*)(As + (c ^ ((c >> 3) & 7)) * 8);
      }
#pragma unroll
      for (int nt = 0; nt < 4; ++nt) {
        int c = (wn * 64 + nt * 16 + l15) * 8 + kh * 4 + lq;
        bf[nt] = *(const f16x8*)(Bs + (c ^ ((c >> 3) & 7)) * 8);
      }
#pragma unroll
      for (int mt = 0; mt < 4; ++mt)
#pragma unroll
        for (int nt = 0; nt < 4; ++nt)
          acc[mt][nt] = __builtin_amdgcn_mfma_f32_16x16x32_f16(af[mt], bf[nt], acc[mt][nt], 0, 0, 0);
    }
  }

#pragma unroll
  for (int mt = 0; mt < 4; ++mt)
#pragma unroll
    for (int nt = 0; nt < 4; ++nt)
#pragma unroll
      for (int r = 0; r < 4; ++r) {
        int row = m0 + wm * 64 + mt * 16 + lq * 4 + r;  // C/D: row=(lane>>4)*4+reg
        int col = n0 + wn * 64 + nt * 16 + l15;         //      col=lane&15
        if (F16OUT)
          ((_Float16*)Cb + (long long)b * sC)[(long long)row * NT + col] = (_Float16)acc[mt][nt][r];
        else
          ((float*)Cb + (long long)b * sC)[(long long)row * NT + col] = acc[mt][nt][r];
      }
}

// ---------------- flash attention v8: MFMA row-sum + skip-rescale ----------------
// pt (B,4096,512): cols 0..255 = phi_T, 256..511 = theta_T (c-contiguous)
// g  (B,256,4096): kv-contiguous.  yT (B,4096,256) f16 out.
// 256 blocks x 512 threads. Group hw=w>>2 owns kv half hw; wave wp=w&3 owns
// 16 q-rows. Per 128-kv t-step: 4 merged phases (2 phi, 2 g), 32KB each into
// a 2-buffer ring; vmcnt(0)+s_barrier per phase; chunk-XOR swizzled staging
// (r4). Softmax: max-butterfly only; row-sum comes from 4 extra MFMAs
// (lacc += P@ones, same C/D layout as yacc); rescale skipped wave-uniformly
// (exact: alpha==1) when no row's max grew this t-step.
__global__ __launch_bounds__(512, 2) void flash_attn3(
    const _Float16* __restrict__ pt, const _Float16* __restrict__ g,
    _Float16* __restrict__ yT) {
  __shared__ _Float16 Stg[2][2][16384];  // per-group 2 x 32KB ring (128KB)
  __shared__ _Float16 Ps[8][2048];       // per-wave P [16q][128kv] A-frag order (32KB)
  const int tid = threadIdx.x, lane = tid & 63, w = tid >> 6;
  const int hw = w >> 2, wp = w & 3;    // kv-half group, wave-in-group
  const int l15 = lane & 15, lq = lane >> 4;

  // XCD swizzle: 2 XCDs per batch -> per-XCD L2 working set = one batch's ~4MB
  const int idx = blockIdx.x;
  const int b = (idx >> 1) & 3;
  const int q0 = (((idx >> 3) << 1) | (idx & 1)) * 64;
  const int kvbase = hw * 2048;
  const _Float16* __restrict__ ptb = pt + (long long)b * NN_SP * 512;
  const _Float16* __restrict__ gb = g + (long long)b * CI * NN_SP;

  // Per-issue lane offsets (frag-order permutation + chunk-XOR), invariant.
  int offPhi[4], offG[4], chw_[4];
#pragma unroll
  for (int j = 0; j < 4; ++j) {
    int u = wp * 256 + j * 64 + lane;
    chw_[j] = wp * 256 + j * 64;
    int us = u ^ ((u >> 3) & 7);   // chunk-XOR: this LDS chunk holds frag 'us'
    int k2 = us >> 9, nv8 = (us >> 6) & 7, r15 = (us >> 2) & 15, rq = us & 3;
    offPhi[j] = (nv8 * 16 + r15) * 512 + k2 * 32 + rq * 8;
    int kq = us >> 8, ct4 = (us >> 6) & 3;
    offG[j] = (ct4 * 16 + r15) * 4096 + kq * 32 + rq * 8;
  }
  // swizzled read index for frag (l15*4+lq) within each 64-chunk group
  const int rswz = (l15 * 4 + lq) ^ ((l15 >> 1) & 7);

  // Q (theta) resident in registers: 16 q-rows (shared with partner wave)
  f16x8 qreg[8];
#pragma unroll
  for (int kk = 0; kk < 8; ++kk)
    qreg[kk] = *(const f16x8*)(
        ptb + (long long)(q0 + wp * 16 + l15) * 512 + 256 + kk * 32 + lq * 8);

  f16x8 onesf;
#pragma unroll
  for (int j = 0; j < 8; ++j) onesf[j] = (_Float16)1.f;

  f32x4 yacc[16];
#pragma unroll
  for (int nt = 0; nt < 16; ++nt) yacc[nt] = (f32x4){0.f, 0.f, 0.f, 0.f};
  f32x4 lacc = (f32x4){0.f, 0.f, 0.f, 0.f};   // row-sums (all cols equal)
  float mrow[4] = {-3e38f, -3e38f, -3e38f, -3e38f};

  // issue merged phase mq (0..63) into this group's buffer bi:
  // two 16KB sub-chunks, 8 async16 per wave.
  auto issue = [&](int mq, int bi) {
    if (mq >= 64) return;            // 16 kv-steps x 4 merged phases per group
    int t = mq >> 2, mp = mq & 3, kv0 = kvbase + t * 128;
#pragma unroll
    for (int hh = 0; hh < 2; ++hh) {
      int sub = mp * 2 + hh;
      _Float16* buf = Stg[hw][bi] + hh * 8192;
      if (sub < 4) {
        const _Float16* basep = ptb + (long long)kv0 * 512 + sub * 64;
#pragma unroll
        for (int j = 0; j < 4; ++j)
          async16(basep + offPhi[j], (void*)(buf + chw_[j] * 8));
      } else {
        const _Float16* baseg = gb + (long long)(sub - 4) * 64 * 4096 + kv0;
#pragma unroll
        for (int j = 0; j < 4; ++j)
          async16(baseg + offG[j], (void*)(buf + chw_[j] * 8));
      }
    }
  };

  int p = 0;               // merged-phase counter; ring buffer = p & 1
  issue(0, 0);

  for (int t = 0; t < 16; ++t) {
    f32x4 S[8];
#pragma unroll
    for (int i = 0; i < 8; ++i) S[i] = (f32x4){0.f, 0.f, 0.f, 0.f};

    // ---- 2 merged phi phases: S = theta @ phi^T ----
#pragma unroll
    for (int mp = 0; mp < 2; ++mp) {
      asm volatile("s_waitcnt vmcnt(0)" ::: "memory");  // own loads for phase p done
      asm volatile("s_barrier" ::: "memory");           // all waves: data in, other buf free
      issue(p + 1, (p + 1) & 1);
      const _Float16* bufb = Stg[hw][p & 1];
      __builtin_amdgcn_s_setprio(1);
#pragma unroll
      for (int hh = 0; hh < 2; ++hh) {
        int c = mp * 2 + hh;
        const _Float16* buf = bufb + hh * 8192;
#pragma unroll
        for (int k2 = 0; k2 < 2; ++k2)
#pragma unroll
          for (int nv = 0; nv < 8; ++nv) {
            f16x8 bf = *(const f16x8*)(buf + (k2 * 512 + nv * 64 + rswz) * 8);
            S[nv] = __builtin_amdgcn_mfma_f32_16x16x32_f16(qreg[c * 2 + k2], bf, S[nv], 0, 0, 0);
          }
      }
      __builtin_amdgcn_s_setprio(0);
      ++p;
    }

    // ---- softmax: max-butterfly + exact conditional rescale ----
    float nm[4];
    int grew = 0;
#pragma unroll
    for (int r = 0; r < 4; ++r) {
      float mx = fmaxf(fmaxf(S[0][r], S[1][r]), fmaxf(S[2][r], S[3][r]));
      mx = fmaxf(mx, fmaxf(fmaxf(S[4][r], S[5][r]), fmaxf(S[6][r], S[7][r])));
#pragma unroll
      for (int d = 1; d < 16; d <<= 1) mx = fmaxf(mx, __shfl_xor(mx, d, 64));
      nm[r] = fmaxf(mrow[r], mx);
      grew |= (mx > mrow[r]);
    }
    if (__ballot(grew)) {   // exact skip: alpha==1 for every row when !grew
      f32x4 al;
#pragma unroll
      for (int r = 0; r < 4; ++r) {
        al[r] = __expf(mrow[r] - nm[r]);
        mrow[r] = nm[r];
      }
#pragma unroll
      for (int nt = 0; nt < 16; ++nt) yacc[nt] *= al;
      lacc *= al;
    }
#pragma unroll
    for (int r = 0; r < 4; ++r)
#pragma unroll
      for (int nv = 0; nv < 8; ++nv) S[nv][r] = __expf(S[nv][r] - mrow[r]);

    // ---- P: C/D regs -> wave-private LDS, XOR-swizzled chunks ----
#pragma unroll
    for (int nv = 0; nv < 8; ++nv) {
      int kq = nv >> 1;
      int lqr = (nv & 1) * 2 + (l15 >> 3);
      int e = l15 & 7;
#pragma unroll
      for (int r = 0; r < 4; ++r) {
        int u = kq * 64 + lqr * 16 + lq * 4 + r;
        int us = u ^ ((u >> 3) & 7);
        Ps[w][us * 8 + e] = (_Float16)S[nv][r];
      }
    }
    f16x8 aP[4];
#pragma unroll
    for (int kq = 0; kq < 4; ++kq) {
      int ur = kq * 64 + lane;
      int urs = ur ^ ((ur >> 3) & 7);
      aP[kq] = *(const f16x8*)(&Ps[w][urs * 8]);
    }

    // ---- row-sum via MFMA (replaces shfl sum-butterfly): lacc += P @ 1 ----
#pragma unroll
    for (int kq = 0; kq < 4; ++kq)
      lacc = __builtin_amdgcn_mfma_f32_16x16x32_f16(aP[kq], onesf, lacc, 0, 0, 0);

    // ---- 2 merged g phases: y += P @ g^T ----
#pragma unroll
    for (int mp = 0; mp < 2; ++mp) {
      asm volatile("s_waitcnt vmcnt(0)" ::: "memory");
      asm volatile("s_barrier" ::: "memory");
      issue(p + 1, (p + 1) & 1);
      const _Float16* bufb = Stg[hw][p & 1];
      __builtin_amdgcn_s_setprio(1);
#pragma unroll
      for (int hh = 0; hh < 2; ++hh) {
        int cg = mp * 2 + hh;
        const _Float16* buf = bufb + hh * 8192;
#pragma unroll
        for (int kq = 0; kq < 4; ++kq)
#pragma unroll
          for (int ct = 0; ct < 4; ++ct) {
            f16x8 bf = *(const f16x8*)(buf + (kq * 256 + ct * 64 + rswz) * 8);
            yacc[cg * 4 + ct] =
                __builtin_amdgcn_mfma_f32_16x16x32_f16(aP[kq], bf, yacc[cg * 4 + ct], 0, 0, 0);
          }
      }
      __builtin_amdgcn_s_setprio(0);
      ++p;
    }
  }

  // ---- in-block f32 merge: group 1 -> LDS, group 0 combines + stores ----
  __syncthreads();  // all waves done with Stg before it is reused
  float* mbuf = (float*)Stg;                    // [64 rows][stride 257] f32 (~66KB)
  float* sbuf = (float*)((char*)Stg + 81920);   // [64 rows][2] f32 (m,l)
  if (hw == 1) {
#pragma unroll
    for (int r = 0; r < 4; ++r) {
      int rr = wp * 16 + lq * 4 + r;
#pragma unroll
      for (int nt = 0; nt < 16; ++nt)
        mbuf[rr * 257 + nt * 16 + l15] = yacc[nt][r];
      if (l15 == 0) {
        sbuf[rr * 2 + 0] = mrow[r];
        sbuf[rr * 2 + 1] = lacc[r];
      }
    }
  }
  __syncthreads();
  if (hw == 0) {
    _Float16* yTb = yT + (long long)b * NN_SP * CI;
#pragma unroll
    for (int r = 0; r < 4; ++r) {
      int rr = wp * 16 + lq * 4 + r;
      float m2 = sbuf[rr * 2 + 0], l2 = sbuf[rr * 2 + 1];
      float m = fmaxf(mrow[r], m2);
      float w1 = __expf(mrow[r] - m), w2 = __expf(m2 - m);
      float inv = 1.f / (w1 * lacc[r] + w2 * l2);
      int row = q0 + rr;
#pragma unroll
      for (int nt = 0; nt < 16; ++nt) {
        float v2 = mbuf[rr * 257 + nt * 16 + l15];
        yTb[(long long)row * CI + nt * 16 + l15] =
            (_Float16)((w1 * yacc[nt][r] + w2 * v2) * inv);
      }
    }
  }
}

extern "C" void kernel_launch(void* const* d_in, const int* in_sizes, int n_in,
                              void* d_out, int out_size, void* d_ws, size_t ws_size,
                              hipStream_t stream) {
  const float* x = (const float*)d_in[0];
  const float* w_phi = (const float*)d_in[1];
  const float* w_theta = (const float*)d_in[2];
  const float* w_g = (const float*)d_in[3];
  const float* w_mask = (const float*)d_in[4];
  float* out = (float*)d_out;
  char* ws = (char*)d_ws;

  // workspace layout (51.4 MB total)
  _Float16* xT = (_Float16*)(ws);                 // (B,4096,512)  16.78 MB
  _Float16* pt = (_Float16*)(ws + 16777216);      // (B,4096,512)  16.78 MB  [phi|theta]
  _Float16* gB = (_Float16*)(ws + 33554432);      // (B,256,4096)   8.39 MB
  _Float16* yT = (_Float16*)(ws + 41943040);      // (B,4096,256)   8.39 MB
  _Float16* wpt = (_Float16*)(ws + 50331648);     // (512,512)
  _Float16* wg = (_Float16*)(ws + 50855936);      // (256,512)
  _Float16* wm = (_Float16*)(ws + 51118080);      // (512,256)

  convert_w<<<2048, 256, 0, stream>>>(w_phi, w_theta, w_g, w_mask, wpt, wg, wm);
  transpose_x<<<dim3(64, 8, 4), 256, 0, stream>>>(x, xT);
  // PT[n, {phi|theta}] = xT @ wpt^T : M=4096, N=512, K=512, per batch
  gemm_bt<4096, 512, 512, true><<<dim3(4, 32, 4), 256, 0, stream>>>(
      xT, wpt, pt, 4096LL * 512, 0, 4096LL * 512);
  // g[c, n] = wg @ x : M=256, N=4096, K=512 (Bt = xT), per batch
  gemm_bt<256, 4096, 512, true><<<dim3(32, 2, 4), 256, 0, stream>>>(
      wg, xT, gB, 0, 4096LL * 512, 256LL * 4096);
  // flash attention v8: 256 blocks x 512 threads
  flash_attn3<<<dim3(256), 512, 0, stream>>>(pt, gB, yT);
  // out[o, n] = wm @ y : M=512, N=4096, K=256 (Bt = yT), fp32 out, per batch
  gemm_bt<512, 4096, 256, false><<<dim3(32, 4, 4), 256, 0, stream>>>(
      wm, yT, out, 0, 4096LL * 256, 512LL * 4096);
}